// Round 3
// baseline (159.446 us; speedup 1.0000x reference)
//
#include <hip/hip_runtime.h>
#include <math.h>

#define NHW 676               // 26*26
#define NB 256
#define NCELLS (NB * NHW)     // 173056 = 676 blocks * 256 threads
#define NC 20                 // classes
#define NA 5                  // anchors

__device__ __forceinline__ float sigmoidf_(float x) {
    return 1.0f / (1.0f + __expf(-x));
}

__global__ __launch_bounds__(256, 3) void yolo_loss_kernel(
    const float* __restrict__ pred,   // (B, 125, 26, 26)
    const float* __restrict__ tgt,    // (B, 26, 26, 25)
    float* __restrict__ out)          // 4 floats
{
    const float AW[NA] = {1.3221f, 3.19275f, 5.05587f, 9.47112f, 11.2364f};
    const float AH[NA] = {1.73145f, 4.00944f, 8.09892f, 4.84053f, 10.0071f};

    __shared__ __align__(16) float stgt[256 * 25];   // 25.6 KB staged target
    __shared__ float sred[4][4];

    const int tid = threadIdx.x;
    const int t0  = blockIdx.x << 8;
    const int t   = t0 + tid;
    const int b   = t / NHW;
    const int hw  = t - b * NHW;
    const float* p = pred + (size_t)b * 125 * NHW + hw;   // channel stride NHW

    // ---- round 1: issue EVERYTHING independent up front ----
    // 25 coalesced box/conf loads
    float v[NA][5];                  // [anchor][tc,tx,ty,tw,th]
    #pragma unroll
    for (int a = 0; a < NA; ++a) {
        #pragma unroll
        for (int c = 0; c < 5; ++c) {
            v[a][c] = p[(a * 25 + 20 + c) * NHW];
        }
    }
    // obj flag via one direct gather (breaks class-load dependency on barrier)
    const float gconf = tgt[(size_t)t * 25 + 20];

    // stage the whole target block as coalesced float4 (1600 float4 per block)
    {
        const float4* g4 = (const float4*)(tgt + (size_t)t0 * 25);
        float4* s4 = (float4*)stgt;
        #pragma unroll
        for (int i = 0; i < 6; ++i) s4[i * 256 + tid] = g4[i * 256 + tid];
        if (tid < 64) s4[1536 + tid] = g4[1536 + tid];
    }

    const bool obj = (gconf != 0.0f);

    // ---- round 2: class logits for ALL anchors, only on obj lanes (~2/wave).
    // No dependency on best_a -> no third latency round.
    float cl[NA][NC];
    if (obj) {
        #pragma unroll
        for (int a = 0; a < NA; ++a) {
            #pragma unroll
            for (int k = 0; k < NC; ++k) {
                cl[a][k] = p[(a * 25 + k) * NHW];
            }
        }
    }

    __syncthreads();
    const float* tg = stgt + tid * 25;   // stride 25 mod 32 -> conflict-free

    const float gx = tg[21], gy = tg[22], gw = tg[23], gh = tg[24];
    const float g_x1 = gx - gw * 0.5f, g_x2 = gx + gw * 0.5f;
    const float g_y1 = gy - gh * 0.5f, g_y2 = gy + gh * 0.5f;
    const float g_area = gw * gh;

    float best_iou = -1.0f;
    int   best_a = 0;
    float bx = 0, by = 0, bw = 0, bh = 0, btc = 0;

    #pragma unroll
    for (int a = 0; a < NA; ++a) {
        float px = sigmoidf_(v[a][1]);
        float py = sigmoidf_(v[a][2]);
        float pw = __expf(v[a][3]) * AW[a];
        float ph = __expf(v[a][4]) * AH[a];
        float iw = fminf(px + pw * 0.5f, g_x2) - fmaxf(px - pw * 0.5f, g_x1);
        float ih = fminf(py + ph * 0.5f, g_y2) - fmaxf(py - ph * 0.5f, g_y1);
        iw = fmaxf(iw, 0.0f);
        ih = fmaxf(ih, 0.0f);
        float inter = iw * ih;
        float uni = pw * ph + g_area - inter;
        float iou = inter / (uni + 1e-10f);
        if (iou > best_iou) {   // strict >: first max wins ties (matches jnp.argmax)
            best_iou = iou;
            best_a = a;
            bx = px; by = py; bw = pw; bh = ph;
            btc = v[a][0];
        }
    }
    const float bconf = sigmoidf_(btc);

    float box_l = 0.0f, conf_l = 0.0f, noobj_l = 0.0f, cls_l = 0.0f;

    if (obj) {
        float dx = bx - gx, dy = by - gy, dw = bw - gw, dh = bh - gh;
        box_l = dx * dx + dy * dy + dw * dw + dh * dh;
        float dc = bconf - gconf;
        conf_l = dc * dc;

        // per-anchor log-softmax NLL, then select best_a via cndmask chain
        float nll[NA];
        #pragma unroll
        for (int a = 0; a < NA; ++a) {
            float m = cl[a][0];
            #pragma unroll
            for (int k = 1; k < NC; ++k) m = fmaxf(m, cl[a][k]);
            float s = 0.0f, lsel = 0.0f;
            #pragma unroll
            for (int k = 0; k < NC; ++k) {
                s += __expf(cl[a][k] - m);
                if (tg[k] > 0.5f) lsel = cl[a][k];   // one-hot from LDS
            }
            nll[a] = -(lsel - m - __logf(s));
        }
        float cls = nll[0];
        #pragma unroll
        for (int a = 1; a < NA; ++a) cls = (best_a == a) ? nll[a] : cls;
        cls_l = cls;
    } else {
        noobj_l = bconf * bconf;
    }

    // ---- wave (64-lane) reduction ----
    #pragma unroll
    for (int off = 32; off > 0; off >>= 1) {
        box_l   += __shfl_down(box_l,   off, 64);
        conf_l  += __shfl_down(conf_l,  off, 64);
        noobj_l += __shfl_down(noobj_l, off, 64);
        cls_l   += __shfl_down(cls_l,   off, 64);
    }

    int wave = tid >> 6;
    int lane = tid & 63;
    if (lane == 0) {
        sred[wave][0] = box_l;
        sred[wave][1] = conf_l;
        sred[wave][2] = noobj_l;
        sred[wave][3] = cls_l;
    }
    __syncthreads();
    if (tid == 0) {
        float b0 = 0, b1 = 0, b2 = 0, b3 = 0;
        #pragma unroll
        for (int w = 0; w < 4; ++w) {
            b0 += sred[w][0];
            b1 += sred[w][1];
            b2 += sred[w][2];
            b3 += sred[w][3];
        }
        atomicAdd(&out[0], b0 * (5.0f / 256.0f));
        atomicAdd(&out[1], b1 * (1.0f / 256.0f));
        atomicAdd(&out[2], b2 * (0.5f / 256.0f));
        atomicAdd(&out[3], b3 * (1.0f / 256.0f));
    }
}

extern "C" void kernel_launch(void* const* d_in, const int* in_sizes, int n_in,
                              void* d_out, int out_size, void* d_ws, size_t ws_size,
                              hipStream_t stream) {
    const float* pred = (const float*)d_in[0];
    const float* tgt  = (const float*)d_in[1];
    float* out = (float*)d_out;

    hipMemsetAsync(out, 0, out_size * sizeof(float), stream);

    dim3 grid(NCELLS / 256);
    dim3 block(256);
    hipLaunchKernelGGL(yolo_loss_kernel, grid, block, 0, stream,
                       pred, tgt, out);
}

// Round 4
// 155.368 us; speedup vs baseline: 1.0262x; 1.0262x over previous
//
#include <hip/hip_runtime.h>
#include <math.h>

#define NHW 676               // 26*26
#define NB 256
#define NCELLS (NB * NHW)     // 173056 = 676 blocks * 256 threads
#define NC 20                 // classes
#define NA 5                  // anchors

__device__ __forceinline__ float sigmoidf_(float x) {
    return 1.0f / (1.0f + __expf(-x));
}

__global__ __launch_bounds__(256) void yolo_loss_kernel(
    const float* __restrict__ pred,   // (B, 125, 26, 26)
    const float* __restrict__ tgt,    // (B, 26, 26, 25)
    float* __restrict__ out)          // 4 floats
{
    __shared__ __align__(16) float stgt[256 * 25];   // 25.6 KB staged target
    __shared__ float sred[4][4];

    const int tid = threadIdx.x;
    const int t0  = blockIdx.x << 8;
    const int t   = t0 + tid;
    const int b   = t / NHW;
    const int hw  = t - b * NHW;
    const float* p = pred + (size_t)b * 125 * NHW + hw;   // channel stride NHW

    // ---- stage target block, coalesced float4 (1600 float4 / block) ----
    {
        const float4* g4 = (const float4*)(tgt + (size_t)t0 * 25);
        float4* s4 = (float4*)stgt;
        #pragma unroll
        for (int i = 0; i < 6; ++i) s4[i * 256 + tid] = g4[i * 256 + tid];
        if (tid < 64) s4[1536 + tid] = g4[1536 + tid];
    }

    // ---- 25 box/conf pred loads: NAMED SCALARS, no arrays -> no scratch ----
#define LD5(a) \
    float tc##a = p[((a)*25 + 20) * NHW]; \
    float tx##a = p[((a)*25 + 21) * NHW]; \
    float ty##a = p[((a)*25 + 22) * NHW]; \
    float tw##a = p[((a)*25 + 23) * NHW]; \
    float th##a = p[((a)*25 + 24) * NHW];
    LD5(0) LD5(1) LD5(2) LD5(3) LD5(4)
#undef LD5

    __syncthreads();
    const float* tg = stgt + tid * 25;   // stride 25 mod 32 -> conflict-free

    const float gconf = tg[20];
    const float gx = tg[21], gy = tg[22], gw = tg[23], gh = tg[24];
    const float g_x1 = gx - gw * 0.5f, g_x2 = gx + gw * 0.5f;
    const float g_y1 = gy - gh * 0.5f, g_y2 = gy + gh * 0.5f;
    const float g_area = gw * gh;

    float best_iou = -1.0f;
    int   best_a = 0;
    float bx = 0.0f, by = 0.0f, bw = 0.0f, bh = 0.0f, btc = 0.0f;

#define IOU_STEP(a, AWc, AHc) { \
    float px = sigmoidf_(tx##a); \
    float py = sigmoidf_(ty##a); \
    float pw = __expf(tw##a) * (AWc); \
    float ph = __expf(th##a) * (AHc); \
    float iw = fminf(px + pw * 0.5f, g_x2) - fmaxf(px - pw * 0.5f, g_x1); \
    float ih = fminf(py + ph * 0.5f, g_y2) - fmaxf(py - ph * 0.5f, g_y1); \
    iw = fmaxf(iw, 0.0f); ih = fmaxf(ih, 0.0f); \
    float inter = iw * ih; \
    float uni = pw * ph + g_area - inter; \
    float iou = inter / (uni + 1e-10f); \
    if (iou > best_iou) { /* strict >: first max wins, matches jnp.argmax */ \
        best_iou = iou; best_a = (a); \
        bx = px; by = py; bw = pw; bh = ph; btc = tc##a; \
    } }
    IOU_STEP(0, 1.3221f,  1.73145f)
    IOU_STEP(1, 3.19275f, 4.00944f)
    IOU_STEP(2, 5.05587f, 8.09892f)
    IOU_STEP(3, 9.47112f, 4.84053f)
    IOU_STEP(4, 11.2364f, 10.0071f)
#undef IOU_STEP

    const float bconf = sigmoidf_(btc);

    float box_l = 0.0f, conf_l = 0.0f, noobj_l = 0.0f, cls_l = 0.0f;

    if (gconf != 0.0f) {
        float dx = bx - gx, dy = by - gy, dw = bw - gw, dh = bh - gh;
        box_l = dx * dx + dy * dy + dw * dw + dh * dh;
        float dc = bconf - gconf;
        conf_l = dc * dc;

        // ---- class NLL for best anchor only: 20 NAMED scalar loads ----
        const float* pc = p + best_a * 25 * NHW;
#define LDC(k) float l##k = pc[(k) * NHW];
        LDC(0) LDC(1) LDC(2) LDC(3) LDC(4) LDC(5) LDC(6) LDC(7) LDC(8) LDC(9)
        LDC(10) LDC(11) LDC(12) LDC(13) LDC(14) LDC(15) LDC(16) LDC(17) LDC(18) LDC(19)
#undef LDC
        float m = l0;
#define MAXC(k) m = fmaxf(m, l##k);
        MAXC(1) MAXC(2) MAXC(3) MAXC(4) MAXC(5) MAXC(6) MAXC(7) MAXC(8) MAXC(9)
        MAXC(10) MAXC(11) MAXC(12) MAXC(13) MAXC(14) MAXC(15) MAXC(16) MAXC(17) MAXC(18) MAXC(19)
#undef MAXC
        float s = 0.0f, lsel = 0.0f;
#define ACC(k) { s += __expf(l##k - m); lsel = fmaf(tg[k], l##k, lsel); }
        ACC(0) ACC(1) ACC(2) ACC(3) ACC(4) ACC(5) ACC(6) ACC(7) ACC(8) ACC(9)
        ACC(10) ACC(11) ACC(12) ACC(13) ACC(14) ACC(15) ACC(16) ACC(17) ACC(18) ACC(19)
#undef ACC
        cls_l = -(lsel - m - __logf(s));
    } else {
        noobj_l = bconf * bconf;
    }

    // ---- wave (64-lane) reduction ----
    #pragma unroll
    for (int off = 32; off > 0; off >>= 1) {
        box_l   += __shfl_down(box_l,   off, 64);
        conf_l  += __shfl_down(conf_l,  off, 64);
        noobj_l += __shfl_down(noobj_l, off, 64);
        cls_l   += __shfl_down(cls_l,   off, 64);
    }

    int wave = tid >> 6;
    int lane = tid & 63;
    if (lane == 0) {
        sred[wave][0] = box_l;
        sred[wave][1] = conf_l;
        sred[wave][2] = noobj_l;
        sred[wave][3] = cls_l;
    }
    __syncthreads();
    if (tid == 0) {
        float b0 = 0, b1 = 0, b2 = 0, b3 = 0;
        #pragma unroll
        for (int w = 0; w < 4; ++w) {
            b0 += sred[w][0];
            b1 += sred[w][1];
            b2 += sred[w][2];
            b3 += sred[w][3];
        }
        atomicAdd(&out[0], b0 * (5.0f / 256.0f));
        atomicAdd(&out[1], b1 * (1.0f / 256.0f));
        atomicAdd(&out[2], b2 * (0.5f / 256.0f));
        atomicAdd(&out[3], b3 * (1.0f / 256.0f));
    }
}

extern "C" void kernel_launch(void* const* d_in, const int* in_sizes, int n_in,
                              void* d_out, int out_size, void* d_ws, size_t ws_size,
                              hipStream_t stream) {
    const float* pred = (const float*)d_in[0];
    const float* tgt  = (const float*)d_in[1];
    float* out = (float*)d_out;

    hipMemsetAsync(out, 0, out_size * sizeof(float), stream);

    dim3 grid(NCELLS / 256);
    dim3 block(256);
    hipLaunchKernelGGL(yolo_loss_kernel, grid, block, 0, stream,
                       pred, tgt, out);
}

// Round 5
// 129.148 us; speedup vs baseline: 1.2346x; 1.2030x over previous
//
#include <hip/hip_runtime.h>
#include <math.h>

#define NHW 676               // 26*26
#define NB 256
#define NCELLS (NB * NHW)     // 173056 = 676 blocks * 256 threads
#define NBLK 676
#define NC 20                 // classes
#define NA 5                  // anchors

__device__ __forceinline__ float sigmoidf_(float x) {
    return 1.0f / (1.0f + __expf(-x));
}

// ---------------- kernel 1: per-cell losses -> per-block float4 partials ----------------
__global__ __launch_bounds__(256) void yolo_loss_kernel(
    const float* __restrict__ pred,   // (B, 125, 26, 26)
    const float* __restrict__ tgt,    // (B, 26, 26, 25)
    float4* __restrict__ part)        // [NBLK] partials: box, conf, noobj, cls
{
    __shared__ __align__(16) float stgt[256 * 25];   // 25.6 KB staged target
    __shared__ float sred[4][4];

    const int tid = threadIdx.x;
    const int t0  = blockIdx.x << 8;
    const int t   = t0 + tid;
    const int b   = t / NHW;
    const int hw  = t - b * NHW;
    const float* p = pred + (size_t)b * 125 * NHW + hw;   // channel stride NHW

    // ---- stage target block, coalesced float4 (1600 float4 / block) ----
    {
        const float4* g4 = (const float4*)(tgt + (size_t)t0 * 25);
        float4* s4 = (float4*)stgt;
        #pragma unroll
        for (int i = 0; i < 6; ++i) s4[i * 256 + tid] = g4[i * 256 + tid];
        if (tid < 64) s4[1536 + tid] = g4[1536 + tid];
    }

    // ---- 25 box/conf pred loads: NAMED SCALARS, no arrays -> no scratch ----
#define LD5(a) \
    float tc##a = p[((a)*25 + 20) * NHW]; \
    float tx##a = p[((a)*25 + 21) * NHW]; \
    float ty##a = p[((a)*25 + 22) * NHW]; \
    float tw##a = p[((a)*25 + 23) * NHW]; \
    float th##a = p[((a)*25 + 24) * NHW];
    LD5(0) LD5(1) LD5(2) LD5(3) LD5(4)
#undef LD5

    __syncthreads();
    const float* tg = stgt + tid * 25;   // stride 25 mod 32 -> conflict-free

    const float gconf = tg[20];
    const float gx = tg[21], gy = tg[22], gw = tg[23], gh = tg[24];
    const float g_x1 = gx - gw * 0.5f, g_x2 = gx + gw * 0.5f;
    const float g_y1 = gy - gh * 0.5f, g_y2 = gy + gh * 0.5f;
    const float g_area = gw * gh;

    float best_iou = -1.0f;
    int   best_a = 0;
    float bx = 0.0f, by = 0.0f, bw = 0.0f, bh = 0.0f, btc = 0.0f;

#define IOU_STEP(a, AWc, AHc) { \
    float px = sigmoidf_(tx##a); \
    float py = sigmoidf_(ty##a); \
    float pw = __expf(tw##a) * (AWc); \
    float ph = __expf(th##a) * (AHc); \
    float iw = fminf(px + pw * 0.5f, g_x2) - fmaxf(px - pw * 0.5f, g_x1); \
    float ih = fminf(py + ph * 0.5f, g_y2) - fmaxf(py - ph * 0.5f, g_y1); \
    iw = fmaxf(iw, 0.0f); ih = fmaxf(ih, 0.0f); \
    float inter = iw * ih; \
    float uni = pw * ph + g_area - inter; \
    float iou = inter / (uni + 1e-10f); \
    if (iou > best_iou) { /* strict >: first max wins, matches jnp.argmax */ \
        best_iou = iou; best_a = (a); \
        bx = px; by = py; bw = pw; bh = ph; btc = tc##a; \
    } }
    IOU_STEP(0, 1.3221f,  1.73145f)
    IOU_STEP(1, 3.19275f, 4.00944f)
    IOU_STEP(2, 5.05587f, 8.09892f)
    IOU_STEP(3, 9.47112f, 4.84053f)
    IOU_STEP(4, 11.2364f, 10.0071f)
#undef IOU_STEP

    const float bconf = sigmoidf_(btc);

    float box_l = 0.0f, conf_l = 0.0f, noobj_l = 0.0f, cls_l = 0.0f;

    if (gconf != 0.0f) {
        float dx = bx - gx, dy = by - gy, dw = bw - gw, dh = bh - gh;
        box_l = dx * dx + dy * dy + dw * dw + dh * dh;
        float dc = bconf - gconf;
        conf_l = dc * dc;

        // ---- class NLL for best anchor only: 20 NAMED scalar loads ----
        const float* pc = p + best_a * 25 * NHW;
#define LDC(k) float l##k = pc[(k) * NHW];
        LDC(0) LDC(1) LDC(2) LDC(3) LDC(4) LDC(5) LDC(6) LDC(7) LDC(8) LDC(9)
        LDC(10) LDC(11) LDC(12) LDC(13) LDC(14) LDC(15) LDC(16) LDC(17) LDC(18) LDC(19)
#undef LDC
        float m = l0;
#define MAXC(k) m = fmaxf(m, l##k);
        MAXC(1) MAXC(2) MAXC(3) MAXC(4) MAXC(5) MAXC(6) MAXC(7) MAXC(8) MAXC(9)
        MAXC(10) MAXC(11) MAXC(12) MAXC(13) MAXC(14) MAXC(15) MAXC(16) MAXC(17) MAXC(18) MAXC(19)
#undef MAXC
        float s = 0.0f, lsel = 0.0f;
#define ACC(k) { s += __expf(l##k - m); lsel = fmaf(tg[k], l##k, lsel); }
        ACC(0) ACC(1) ACC(2) ACC(3) ACC(4) ACC(5) ACC(6) ACC(7) ACC(8) ACC(9)
        ACC(10) ACC(11) ACC(12) ACC(13) ACC(14) ACC(15) ACC(16) ACC(17) ACC(18) ACC(19)
#undef ACC
        cls_l = -(lsel - m - __logf(s));
    } else {
        noobj_l = bconf * bconf;
    }

    // ---- wave (64-lane) reduction ----
    #pragma unroll
    for (int off = 32; off > 0; off >>= 1) {
        box_l   += __shfl_down(box_l,   off, 64);
        conf_l  += __shfl_down(conf_l,  off, 64);
        noobj_l += __shfl_down(noobj_l, off, 64);
        cls_l   += __shfl_down(cls_l,   off, 64);
    }

    int wave = tid >> 6;
    int lane = tid & 63;
    if (lane == 0) {
        sred[wave][0] = box_l;
        sred[wave][1] = conf_l;
        sred[wave][2] = noobj_l;
        sred[wave][3] = cls_l;
    }
    __syncthreads();
    if (tid == 0) {
        float4 r;
        r.x = sred[0][0] + sred[1][0] + sred[2][0] + sred[3][0];
        r.y = sred[0][1] + sred[1][1] + sred[2][1] + sred[3][1];
        r.z = sred[0][2] + sred[1][2] + sred[2][2] + sred[3][2];
        r.w = sred[0][3] + sred[1][3] + sred[2][3] + sred[3][3];
        part[blockIdx.x] = r;   // plain store, zero contention
    }
}

// ---------------- kernel 2: reduce NBLK float4 partials -> 4 scaled outputs ----------------
__global__ __launch_bounds__(256) void yolo_reduce_kernel(
    const float* __restrict__ part,   // NBLK * 4 floats
    float* __restrict__ out)          // 4 floats
{
    const int wave = threadIdx.x >> 6;   // component: 0=box 1=conf 2=noobj 3=cls
    const int lane = threadIdx.x & 63;

    float s = 0.0f;
    for (int j = lane; j < NBLK; j += 64) {
        s += part[j * 4 + wave];
    }
    #pragma unroll
    for (int off = 32; off > 0; off >>= 1) {
        s += __shfl_down(s, off, 64);
    }
    if (lane == 0) {
        const float scale[4] = {5.0f / 256.0f, 1.0f / 256.0f, 0.5f / 256.0f, 1.0f / 256.0f};
        out[wave] = s * scale[wave];
    }
}

extern "C" void kernel_launch(void* const* d_in, const int* in_sizes, int n_in,
                              void* d_out, int out_size, void* d_ws, size_t ws_size,
                              hipStream_t stream) {
    const float* pred = (const float*)d_in[0];
    const float* tgt  = (const float*)d_in[1];
    float* out = (float*)d_out;
    float4* part = (float4*)d_ws;

    hipLaunchKernelGGL(yolo_loss_kernel, dim3(NCELLS / 256), dim3(256), 0, stream,
                       pred, tgt, part);
    hipLaunchKernelGGL(yolo_reduce_kernel, dim3(1), dim3(256), 0, stream,
                       (const float*)part, out);
}